// Round 5
// baseline (355.116 us; speedup 1.0000x reference)
//
#include <hip/hip_runtime.h>
#include <hip/hip_bf16.h>

// GCN encoder: h = relu(Agg(h @ W)) x3 after input linear.
// N=20000 nodes, E=640000 edges, H=128.
// R1->R2: CSR pull-agg replaced atomics (3330->367us).
// R2->R3: bigger GEMM tiles (367->331us).
// R3->R4: parallel scan; 128-row GEMM blocks (331->274us).
// R4->R5: GEMM restructured so each wave owns 8 rows: A comes from global as
//         wave-uniform broadcast loads (no LDS staging of A; LDS instr pressure
//         was the wall at ~2.3x FMA cycles). GEMM epilogue pre-scales rows by
//         dis -> agg inner loop is load+add only (no dis gather, no shfl:
//         edge indices read as wave-uniform scalar loads, 8 in flight).
// ws layout: [dis: N f][off: N i][csr: E i][hA: N*128 f][xw: N*128 f]
// (scan block-sums live in csr[0..19] until k_fill overwrites them)

#define HDIM 128
#define SCAN_TILE 1024

__global__ __launch_bounds__(256) void k_zero(int* __restrict__ off, int N) {
    int i = blockIdx.x * 256 + threadIdx.x;
    if (i < N) off[i] = 0;
}

__global__ __launch_bounds__(256) void k_count(const int* __restrict__ dst,
                                               int* __restrict__ off, int E) {
    int e = blockIdx.x * 256 + threadIdx.x;
    if (e < E) atomicAdd(&off[dst[e]], 1);
}

// Block-local exclusive scan of deg (in place) + dis = rsqrt(deg+1) + block sums.
__global__ __launch_bounds__(256) void k_scan_blk(int* __restrict__ off,
                                                  float* __restrict__ dis,
                                                  int* __restrict__ bsum, int N) {
    int t = threadIdx.x;
    int base = blockIdx.x * SCAN_TILE + t * 4;
    int4 d = make_int4(0, 0, 0, 0);
    if (base + 3 < N) d = *(const int4*)(off + base);
    else {
        if (base + 0 < N) d.x = off[base + 0];
        if (base + 1 < N) d.y = off[base + 1];
        if (base + 2 < N) d.z = off[base + 2];
    }
    if (base + 0 < N) dis[base + 0] = rsqrtf((float)(d.x + 1));
    if (base + 1 < N) dis[base + 1] = rsqrtf((float)(d.y + 1));
    if (base + 2 < N) dis[base + 2] = rsqrtf((float)(d.z + 1));
    if (base + 3 < N) dis[base + 3] = rsqrtf((float)(d.w + 1));

    int tsum = d.x + d.y + d.z + d.w;
    int lane = t & 63;
    int incl = tsum;
    #pragma unroll
    for (int ofs = 1; ofs < 64; ofs <<= 1) {
        int u = __shfl_up(incl, ofs);
        if (lane >= ofs) incl += u;
    }
    __shared__ int wsum[4];
    if (lane == 63) wsum[t >> 6] = incl;
    __syncthreads();
    int w = t >> 6;
    int woff = 0;
    for (int i = 0; i < w; ++i) woff += wsum[i];

    int run = woff + incl - tsum;  // exclusive prefix (block-local)
    if (base + 0 < N) off[base + 0] = run; run += d.x;
    if (base + 1 < N) off[base + 1] = run; run += d.y;
    if (base + 2 < N) off[base + 2] = run; run += d.z;
    if (base + 3 < N) off[base + 3] = run;
    if (t == 255) bsum[blockIdx.x] = woff + incl;  // block total
}

__global__ __launch_bounds__(256) void k_scan_add(int* __restrict__ off,
                                                  const int* __restrict__ bsum, int N) {
    int bid = blockIdx.x;
    if (bid == 0) return;
    int p = 0;
    for (int i = 0; i < bid; ++i) p += bsum[i];
    int base = bid * SCAN_TILE + threadIdx.x * 4;
    if (base + 3 < N) {
        int4 v = *(const int4*)(off + base);
        v.x += p; v.y += p; v.z += p; v.w += p;
        *(int4*)(off + base) = v;
    } else {
        if (base + 0 < N) off[base + 0] += p;
        if (base + 1 < N) off[base + 1] += p;
        if (base + 2 < N) off[base + 2] += p;
    }
}

// csr fill: pos = off[dst]++ ; csr[pos] = src. After this, off[v] = excl_prefix[v+1].
__global__ __launch_bounds__(256) void k_fill(const int* __restrict__ src,
                                              const int* __restrict__ dst,
                                              int* __restrict__ off,
                                              int* __restrict__ csr, int E) {
    int e = blockIdx.x * 256 + threadIdx.x;
    if (e >= E) return;
    int pos = atomicAdd(&off[dst[e]], 1);
    csr[pos] = src[e];
}

// out[N,128] = (A[N,128] @ W[128,128] (+ b)) * scale[row]   (scale optional)
// 512 threads = 8 waves, 64 rows/block; wave owns 8 rows, lane owns 2 cols.
// A[r][k] is wave-uniform -> global broadcast loads (scalarized); only W in LDS.
__global__ __launch_bounds__(512) void k_gemm(const float* __restrict__ A,
                                              const float* __restrict__ W,
                                              const float* __restrict__ b,
                                              const float* __restrict__ scale,
                                              float* __restrict__ out, int N) {
    __shared__ float Wl[HDIM * HDIM];     // 64KB
    int tid = threadIdx.x;

    // stage W: 4096 float4 / 512 threads = 8 each, coalesced
    {
        const float4* W4 = (const float4*)W;
        float4* Wl4 = (float4*)Wl;
        #pragma unroll
        for (int i = 0; i < 8; ++i) Wl4[tid + i * 512] = W4[tid + i * 512];
    }

    int lane = tid & 63;
    int wv = tid >> 6;                       // 0..7
    int r0 = blockIdx.x * 64 + wv * 8;

    // wave-uniform row pointers (clamped for OOB rows; their results are not stored)
    const float* Arp[8];
    #pragma unroll
    for (int r = 0; r < 8; ++r) {
        int rr = r0 + r; if (rr > N - 1) rr = N - 1;
        rr = __builtin_amdgcn_readfirstlane(rr);
        Arp[r] = A + (long long)rr * HDIM;
    }

    float2 acc[8];
    float2 bb = make_float2(0.f, 0.f);
    if (b) bb = ((const float2*)b)[lane];
    #pragma unroll
    for (int r = 0; r < 8; ++r) acc[r] = bb;

    // preload first A chunk (k=0..3) while W staging drains
    float4 aA[8], aB[8];
    #pragma unroll
    for (int r = 0; r < 8; ++r) aA[r] = *(const float4*)(Arp[r]);

    __syncthreads();
    const float2* Wl2 = (const float2*)Wl;   // [k][64 x float2]

#define FMASTEP(aarr, kk)                                                        \
    {                                                                            \
        float2 w0 = Wl2[(kk + 0) * 64 + lane];                                   \
        float2 w1 = Wl2[(kk + 1) * 64 + lane];                                   \
        float2 w2 = Wl2[(kk + 2) * 64 + lane];                                   \
        float2 w3 = Wl2[(kk + 3) * 64 + lane];                                   \
        _Pragma("unroll")                                                        \
        for (int r = 0; r < 8; ++r) {                                            \
            float4 a = aarr[r];                                                  \
            acc[r].x = fmaf(a.x, w0.x, fmaf(a.y, w1.x,                           \
                       fmaf(a.z, w2.x, fmaf(a.w, w3.x, acc[r].x))));             \
            acc[r].y = fmaf(a.x, w0.y, fmaf(a.y, w1.y,                           \
                       fmaf(a.z, w2.y, fmaf(a.w, w3.y, acc[r].y))));             \
        }                                                                        \
    }

    #pragma unroll 2
    for (int k = 0; k < HDIM; k += 8) {
        #pragma unroll
        for (int r = 0; r < 8; ++r) aB[r] = *(const float4*)(Arp[r] + k + 4);
        FMASTEP(aA, k);
        if (k < HDIM - 8) {
            #pragma unroll
            for (int r = 0; r < 8; ++r) aA[r] = *(const float4*)(Arp[r] + k + 8);
        }
        FMASTEP(aB, k + 4);
    }
#undef FMASTEP

    #pragma unroll
    for (int r = 0; r < 8; ++r) {
        int rr = r0 + r;
        if (rr < N) {
            float sc = scale ? scale[rr] : 1.0f;
            float2 o = make_float2(acc[r].x * sc, acc[r].y * sc);
            *((float2*)(out + (long long)rr * HDIM) + lane) = o;
        }
    }
}

// Pull aggregation over pre-scaled xw' (xw' = dis[row] * (h@W)).
// acc = xw'[v] + sum_{u in N(v)} xw'[u];  out = relu(dv*acc + b).
// One wave per node (grid-stride). Edge indices via wave-uniform scalar loads,
// 8 independent row gathers in flight.
__global__ __launch_bounds__(256) void k_agg(const int* __restrict__ off,
                                             const int* __restrict__ csr,
                                             const float* __restrict__ dis,
                                             const float* __restrict__ xw,
                                             const float* __restrict__ b,
                                             float* __restrict__ out, int N) {
    int nwaves = gridDim.x * 4;
    int wid = blockIdx.x * 4 + (threadIdx.x >> 6);
    int lane = threadIdx.x & 63;
    float2 bb = ((const float2*)b)[lane];

    for (int v = wid; v < N; v += nwaves) {
        int start = (v > 0) ? off[v - 1] : 0;   // off is post-fill: off[v] = excl[v+1]
        int end = off[v];
        float dv = dis[v];

        float2 acc = *((const float2*)(xw + (long long)v * HDIM) + lane);  // self term

        int i = start;
        for (; i + 8 <= end; i += 8) {
            int ib = __builtin_amdgcn_readfirstlane(i);
            int s0 = csr[ib + 0], s1 = csr[ib + 1], s2 = csr[ib + 2], s3 = csr[ib + 3];
            int s4 = csr[ib + 4], s5 = csr[ib + 5], s6 = csr[ib + 6], s7 = csr[ib + 7];
            float2 x0 = *((const float2*)(xw + (long long)s0 * HDIM) + lane);
            float2 x1 = *((const float2*)(xw + (long long)s1 * HDIM) + lane);
            float2 x2 = *((const float2*)(xw + (long long)s2 * HDIM) + lane);
            float2 x3 = *((const float2*)(xw + (long long)s3 * HDIM) + lane);
            float2 x4 = *((const float2*)(xw + (long long)s4 * HDIM) + lane);
            float2 x5 = *((const float2*)(xw + (long long)s5 * HDIM) + lane);
            float2 x6 = *((const float2*)(xw + (long long)s6 * HDIM) + lane);
            float2 x7 = *((const float2*)(xw + (long long)s7 * HDIM) + lane);
            acc.x += ((x0.x + x1.x) + (x2.x + x3.x)) + ((x4.x + x5.x) + (x6.x + x7.x));
            acc.y += ((x0.y + x1.y) + (x2.y + x3.y)) + ((x4.y + x5.y) + (x6.y + x7.y));
        }
        for (; i < end; ++i) {
            int s = csr[__builtin_amdgcn_readfirstlane(i)];
            float2 x0 = *((const float2*)(xw + (long long)s * HDIM) + lane);
            acc.x += x0.x; acc.y += x0.y;
        }

        float2 o;
        o.x = fmaxf(fmaf(dv, acc.x, bb.x), 0.f);
        o.y = fmaxf(fmaf(dv, acc.y, bb.y), 0.f);
        *((float2*)(out + (long long)v * HDIM) + lane) = o;
    }
}

extern "C" void kernel_launch(void* const* d_in, const int* in_sizes, int n_in,
                              void* d_out, int out_size, void* d_ws, size_t ws_size,
                              hipStream_t stream) {
    const float* x    = (const float*)d_in[0];
    const int*   ei   = (const int*)d_in[1];   // [2, E]: first E = src, next E = dst
    const float* W_in = (const float*)d_in[2];
    const float* b_in = (const float*)d_in[3];
    const float* Ws   = (const float*)d_in[4]; // [3,128,128]
    const float* bs   = (const float*)d_in[5]; // [3,128]

    const int N = in_sizes[0] / HDIM;
    const int E = in_sizes[1] / 2;
    const int* src = ei;
    const int* dst = ei + E;

    float* dis = (float*)d_ws;                       // N floats
    int*   off = (int*)(dis + N);                    // N ints
    int*   csr = off + N;                            // E ints (first ~32 = scan bsums, transient)
    float* hA  = (float*)(csr + E);                  // N*128 floats (h / agg out)
    float* xw  = hA + (long long)N * HDIM;           // N*128 floats (pre-scaled by dis)

    int nb_N    = (N + 255) / 256;
    int nb_E    = (E + 255) / 256;
    int nb_scan = (N + SCAN_TILE - 1) / SCAN_TILE;
    int nb_gemm = (N + 63) / 64;
    int nb_agg  = 2048;

    // CSR build + dis
    k_zero    <<<nb_N,    256, 0, stream>>>(off, N);
    k_count   <<<nb_E,    256, 0, stream>>>(dst, off, E);
    k_scan_blk<<<nb_scan, 256, 0, stream>>>(off, dis, csr, N);
    k_scan_add<<<nb_scan, 256, 0, stream>>>(off, csr, N);
    k_fill    <<<nb_E,    256, 0, stream>>>(src, dst, off, csr, E);

    // h = x @ W_in + b_in   (no scale)
    k_gemm<<<nb_gemm, 512, 0, stream>>>(x, W_in, b_in, nullptr, hA, N);

    for (int layer = 0; layer < 3; ++layer) {
        const float* W = Ws + (long long)layer * HDIM * HDIM;
        const float* b = bs + (long long)layer * HDIM;
        // xw' = (h @ W) * dis[row]   (no bias)
        k_gemm<<<nb_gemm, 512, 0, stream>>>(hA, W, nullptr, dis, xw, N);
        float* out = (layer == 2) ? (float*)d_out : hA;
        k_agg<<<nb_agg, 256, 0, stream>>>(off, csr, dis, xw, b, out, N);
    }
}

// Round 6
// 282.390 us; speedup vs baseline: 1.2575x; 1.2575x over previous
//
#include <hip/hip_runtime.h>
#include <hip/hip_bf16.h>

// GCN encoder: h = relu(Agg(h @ W)) x3 after input linear.
// N=20000 nodes, E=640000 edges, H=128.
// R1->R2: CSR pull-agg replaced atomics (3330->367us).
// R2->R3: bigger GEMM tiles (367->331us).
// R3->R4: parallel scan; 128-row GEMM blocks (331->274us).
// R4->R5: wave-uniform A from GLOBAL -> latency-bound regression (GEMM 23->55us,
//         VALUBusy 17%): L2 latency not hidden at 2 blocks/CU. Agg scalar-load
//         rewrite helped (~50->35us).
// R5->R6: same wave-owns-8-rows GEMM but A broadcasts come from LDS:
//         32-row A tile (16KB) + W (64KB) = 80KB -> 2 blocks/CU, grid=625.
//         Broadcast LDS reads are conflict-free; W reads 512B/wave/k ->
//         LDS pipe ~400cy/CU per chunk vs 512cy FMA -> FMA-bound.
// ws layout: [dis: N f][off: N i][csr: E i][hA: N*128 f][xw: N*128 f]
// (scan block-sums live in csr[0..19] until k_fill overwrites them)

#define HDIM 128
#define SCAN_TILE 1024

__global__ __launch_bounds__(256) void k_zero(int* __restrict__ off, int N) {
    int i = blockIdx.x * 256 + threadIdx.x;
    if (i < N) off[i] = 0;
}

__global__ __launch_bounds__(256) void k_count(const int* __restrict__ dst,
                                               int* __restrict__ off, int E) {
    int e = blockIdx.x * 256 + threadIdx.x;
    if (e < E) atomicAdd(&off[dst[e]], 1);
}

// Block-local exclusive scan of deg (in place) + dis = rsqrt(deg+1) + block sums.
__global__ __launch_bounds__(256) void k_scan_blk(int* __restrict__ off,
                                                  float* __restrict__ dis,
                                                  int* __restrict__ bsum, int N) {
    int t = threadIdx.x;
    int base = blockIdx.x * SCAN_TILE + t * 4;
    int4 d = make_int4(0, 0, 0, 0);
    if (base + 3 < N) d = *(const int4*)(off + base);
    else {
        if (base + 0 < N) d.x = off[base + 0];
        if (base + 1 < N) d.y = off[base + 1];
        if (base + 2 < N) d.z = off[base + 2];
    }
    if (base + 0 < N) dis[base + 0] = rsqrtf((float)(d.x + 1));
    if (base + 1 < N) dis[base + 1] = rsqrtf((float)(d.y + 1));
    if (base + 2 < N) dis[base + 2] = rsqrtf((float)(d.z + 1));
    if (base + 3 < N) dis[base + 3] = rsqrtf((float)(d.w + 1));

    int tsum = d.x + d.y + d.z + d.w;
    int lane = t & 63;
    int incl = tsum;
    #pragma unroll
    for (int ofs = 1; ofs < 64; ofs <<= 1) {
        int u = __shfl_up(incl, ofs);
        if (lane >= ofs) incl += u;
    }
    __shared__ int wsum[4];
    if (lane == 63) wsum[t >> 6] = incl;
    __syncthreads();
    int w = t >> 6;
    int woff = 0;
    for (int i = 0; i < w; ++i) woff += wsum[i];

    int run = woff + incl - tsum;  // exclusive prefix (block-local)
    if (base + 0 < N) off[base + 0] = run; run += d.x;
    if (base + 1 < N) off[base + 1] = run; run += d.y;
    if (base + 2 < N) off[base + 2] = run; run += d.z;
    if (base + 3 < N) off[base + 3] = run;
    if (t == 255) bsum[blockIdx.x] = woff + incl;  // block total
}

__global__ __launch_bounds__(256) void k_scan_add(int* __restrict__ off,
                                                  const int* __restrict__ bsum, int N) {
    int bid = blockIdx.x;
    if (bid == 0) return;
    int p = 0;
    for (int i = 0; i < bid; ++i) p += bsum[i];
    int base = bid * SCAN_TILE + threadIdx.x * 4;
    if (base + 3 < N) {
        int4 v = *(const int4*)(off + base);
        v.x += p; v.y += p; v.z += p; v.w += p;
        *(int4*)(off + base) = v;
    } else {
        if (base + 0 < N) off[base + 0] += p;
        if (base + 1 < N) off[base + 1] += p;
        if (base + 2 < N) off[base + 2] += p;
    }
}

// csr fill: pos = off[dst]++ ; csr[pos] = src. After this, off[v] = excl_prefix[v+1].
__global__ __launch_bounds__(256) void k_fill(const int* __restrict__ src,
                                              const int* __restrict__ dst,
                                              int* __restrict__ off,
                                              int* __restrict__ csr, int E) {
    int e = blockIdx.x * 256 + threadIdx.x;
    if (e >= E) return;
    int pos = atomicAdd(&off[dst[e]], 1);
    csr[pos] = src[e];
}

// out[N,128] = (A[N,128] @ W[128,128] (+ b)) * scale[row]   (scale optional)
// 256 threads = 4 waves, 32 rows/block; wave owns 8 rows, lane owns 2 cols.
// W (64KB) + A-tile (16KB) in LDS -> 2 blocks/CU. A reads are same-address
// broadcasts (free); W reads 4 b64/chunk. Register double-buffered.
__global__ __launch_bounds__(256) void k_gemm(const float* __restrict__ A,
                                              const float* __restrict__ W,
                                              const float* __restrict__ b,
                                              const float* __restrict__ scale,
                                              float* __restrict__ out, int N) {
    __shared__ float Wl[HDIM * HDIM];     // 64KB
    __shared__ float Al[32 * HDIM];       // 16KB
    int tid = threadIdx.x;
    int block_row = blockIdx.x * 32;

    // stage W: 4096 float4 / 256 threads = 16 each, coalesced
    {
        const float4* W4 = (const float4*)W;
        float4* Wl4 = (float4*)Wl;
        #pragma unroll
        for (int i = 0; i < 16; ++i) Wl4[tid + i * 256] = W4[tid + i * 256];
    }
    // stage A: 1024 float4 / 256 threads = 4 each, zero-pad OOB rows
    {
        const float4* A4 = (const float4*)(A + (long long)block_row * HDIM);
        float4* Al4 = (float4*)Al;
        #pragma unroll
        for (int i = 0; i < 4; ++i) {
            int idx = tid + i * 256;          // float4 index; row = idx>>5
            float4 v = make_float4(0.f, 0.f, 0.f, 0.f);
            if (block_row + (idx >> 5) < N) v = A4[idx];
            Al4[idx] = v;
        }
    }
    __syncthreads();

    int lane = tid & 63;
    int wv = tid >> 6;                       // 0..3
    const float* Ar = Al + wv * 8 * HDIM;    // wave's 8 rows (broadcast reads)
    const float2* Wl2 = (const float2*)Wl;   // [k][64 x float2]

    float2 bb = make_float2(0.f, 0.f);
    if (b) bb = ((const float2*)b)[lane];
    float2 acc[8];
    #pragma unroll
    for (int r = 0; r < 8; ++r) acc[r] = bb;

    float4 aA[8];
    float2 wA[4];
    #pragma unroll
    for (int r = 0; r < 8; ++r) aA[r] = *(const float4*)(Ar + r * HDIM);
    #pragma unroll
    for (int q = 0; q < 4; ++q) wA[q] = Wl2[q * 64 + lane];

    #pragma unroll 4
    for (int k = 0; k < HDIM; k += 4) {
        float4 aB[8];
        float2 wB[4];
        if (k + 4 < HDIM) {
            #pragma unroll
            for (int q = 0; q < 4; ++q) wB[q] = Wl2[(k + 4 + q) * 64 + lane];
            #pragma unroll
            for (int r = 0; r < 8; ++r) aB[r] = *(const float4*)(Ar + r * HDIM + k + 4);
        }
        #pragma unroll
        for (int r = 0; r < 8; ++r) {
            float4 a = aA[r];
            acc[r].x = fmaf(a.x, wA[0].x, fmaf(a.y, wA[1].x,
                       fmaf(a.z, wA[2].x, fmaf(a.w, wA[3].x, acc[r].x))));
            acc[r].y = fmaf(a.x, wA[0].y, fmaf(a.y, wA[1].y,
                       fmaf(a.z, wA[2].y, fmaf(a.w, wA[3].y, acc[r].y))));
        }
        if (k + 4 < HDIM) {
            #pragma unroll
            for (int r = 0; r < 8; ++r) aA[r] = aB[r];
            #pragma unroll
            for (int q = 0; q < 4; ++q) wA[q] = wB[q];
        }
    }

    int r0 = block_row + wv * 8;
    #pragma unroll
    for (int r = 0; r < 8; ++r) {
        int rr = r0 + r;
        if (rr < N) {
            float sc = scale ? scale[rr] : 1.0f;
            float2 o = make_float2(acc[r].x * sc, acc[r].y * sc);
            *((float2*)(out + (long long)rr * HDIM) + lane) = o;
        }
    }
}

// Pull aggregation over pre-scaled xw' (xw' = dis[row] * (h@W)).
// acc = xw'[v] + sum_{u in N(v)} xw'[u];  out = relu(dv*acc + b).
// One wave per node (grid-stride). Edge indices via wave-uniform scalar loads,
// 8 independent row gathers in flight.
__global__ __launch_bounds__(256) void k_agg(const int* __restrict__ off,
                                             const int* __restrict__ csr,
                                             const float* __restrict__ dis,
                                             const float* __restrict__ xw,
                                             const float* __restrict__ b,
                                             float* __restrict__ out, int N) {
    int nwaves = gridDim.x * 4;
    int wid = blockIdx.x * 4 + (threadIdx.x >> 6);
    int lane = threadIdx.x & 63;
    float2 bb = ((const float2*)b)[lane];

    for (int v = wid; v < N; v += nwaves) {
        int start = (v > 0) ? off[v - 1] : 0;   // off is post-fill: off[v] = excl[v+1]
        int end = off[v];
        float dv = dis[v];

        float2 acc = *((const float2*)(xw + (long long)v * HDIM) + lane);  // self term

        int i = start;
        for (; i + 8 <= end; i += 8) {
            int ib = __builtin_amdgcn_readfirstlane(i);
            int s0 = csr[ib + 0], s1 = csr[ib + 1], s2 = csr[ib + 2], s3 = csr[ib + 3];
            int s4 = csr[ib + 4], s5 = csr[ib + 5], s6 = csr[ib + 6], s7 = csr[ib + 7];
            float2 x0 = *((const float2*)(xw + (long long)s0 * HDIM) + lane);
            float2 x1 = *((const float2*)(xw + (long long)s1 * HDIM) + lane);
            float2 x2 = *((const float2*)(xw + (long long)s2 * HDIM) + lane);
            float2 x3 = *((const float2*)(xw + (long long)s3 * HDIM) + lane);
            float2 x4 = *((const float2*)(xw + (long long)s4 * HDIM) + lane);
            float2 x5 = *((const float2*)(xw + (long long)s5 * HDIM) + lane);
            float2 x6 = *((const float2*)(xw + (long long)s6 * HDIM) + lane);
            float2 x7 = *((const float2*)(xw + (long long)s7 * HDIM) + lane);
            acc.x += ((x0.x + x1.x) + (x2.x + x3.x)) + ((x4.x + x5.x) + (x6.x + x7.x));
            acc.y += ((x0.y + x1.y) + (x2.y + x3.y)) + ((x4.y + x5.y) + (x6.y + x7.y));
        }
        for (; i < end; ++i) {
            int s = csr[__builtin_amdgcn_readfirstlane(i)];
            float2 x0 = *((const float2*)(xw + (long long)s * HDIM) + lane);
            acc.x += x0.x; acc.y += x0.y;
        }

        float2 o;
        o.x = fmaxf(fmaf(dv, acc.x, bb.x), 0.f);
        o.y = fmaxf(fmaf(dv, acc.y, bb.y), 0.f);
        *((float2*)(out + (long long)v * HDIM) + lane) = o;
    }
}

extern "C" void kernel_launch(void* const* d_in, const int* in_sizes, int n_in,
                              void* d_out, int out_size, void* d_ws, size_t ws_size,
                              hipStream_t stream) {
    const float* x    = (const float*)d_in[0];
    const int*   ei   = (const int*)d_in[1];   // [2, E]: first E = src, next E = dst
    const float* W_in = (const float*)d_in[2];
    const float* b_in = (const float*)d_in[3];
    const float* Ws   = (const float*)d_in[4]; // [3,128,128]
    const float* bs   = (const float*)d_in[5]; // [3,128]

    const int N = in_sizes[0] / HDIM;
    const int E = in_sizes[1] / 2;
    const int* src = ei;
    const int* dst = ei + E;

    float* dis = (float*)d_ws;                       // N floats
    int*   off = (int*)(dis + N);                    // N ints
    int*   csr = off + N;                            // E ints (first ~32 = scan bsums, transient)
    float* hA  = (float*)(csr + E);                  // N*128 floats (h / agg out)
    float* xw  = hA + (long long)N * HDIM;           // N*128 floats (pre-scaled by dis)

    int nb_N    = (N + 255) / 256;
    int nb_E    = (E + 255) / 256;
    int nb_scan = (N + SCAN_TILE - 1) / SCAN_TILE;
    int nb_gemm = (N + 31) / 32;
    int nb_agg  = 2048;

    // CSR build + dis
    k_zero    <<<nb_N,    256, 0, stream>>>(off, N);
    k_count   <<<nb_E,    256, 0, stream>>>(dst, off, E);
    k_scan_blk<<<nb_scan, 256, 0, stream>>>(off, dis, csr, N);
    k_scan_add<<<nb_scan, 256, 0, stream>>>(off, csr, N);
    k_fill    <<<nb_E,    256, 0, stream>>>(src, dst, off, csr, E);

    // h = x @ W_in + b_in   (no scale)
    k_gemm<<<nb_gemm, 256, 0, stream>>>(x, W_in, b_in, nullptr, hA, N);

    for (int layer = 0; layer < 3; ++layer) {
        const float* W = Ws + (long long)layer * HDIM * HDIM;
        const float* b = bs + (long long)layer * HDIM;
        // xw' = (h @ W) * dis[row]   (no bias)
        k_gemm<<<nb_gemm, 256, 0, stream>>>(hA, W, nullptr, dis, xw, N);
        float* out = (layer == 2) ? (float*)d_out : hA;
        k_agg<<<nb_agg, 256, 0, stream>>>(off, csr, dis, xw, b, out, N);
    }
}

// Round 7
// 245.606 us; speedup vs baseline: 1.4459x; 1.1498x over previous
//
#include <hip/hip_runtime.h>
#include <hip/hip_bf16.h>

// GCN encoder: h = relu(Agg(h @ W)) x3 after input linear.
// N=20000 nodes, E=640000 edges, H=128.
// R1->R2: CSR pull-agg replaced atomics (3330->367us).
// R2->R3: bigger GEMM tiles (367->331us).
// R3->R4: parallel scan; 128-row GEMM blocks (331->274us).
// R4->R5: global-broadcast GEMM -> latency-bound regression (355us).
// R5->R6: LDS-broadcast GEMM (282us) -- still LDS-pipe-bound (~35us/GEMM).
// R6->R7: GEMMs moved to the matrix pipe via 3-term bf16 split
//         (h@W ~= hi@Whi + hi@Wlo + lo@Whi, rel err ~2^-16):
//         h kept as bf16 hi/lo pair (same bytes as fp32 h), W pre-converted
//         once into MFMA B-fragment layout in d_out's tail (512KB scratch,
//         overwritten by the final agg). mfma_f32_16x16x32_bf16,
//         C layout col=lane&15,row=(lane>>4)*4+reg (guide-verified).
// ws layout: [dis: N f][off: N i][csr: E i][hh: N*128 bf16][hl: N*128 bf16][xw: N*128 f]

#define HDIM 128
#define SCAN_TILE 1024

typedef __attribute__((ext_vector_type(8))) short s8v;
typedef __attribute__((ext_vector_type(4))) float f4v;

__device__ __forceinline__ ushort f2bf(float f) {
    uint u = __float_as_uint(f);
    u += 0x7FFFu + ((u >> 16) & 1u);      // round-to-nearest-even
    return (ushort)(u >> 16);
}
__device__ __forceinline__ float bf2f(ushort h) {
    return __uint_as_float(((uint)h) << 16);
}

__global__ __launch_bounds__(256) void k_zero(int* __restrict__ off, int N) {
    int i = blockIdx.x * 256 + threadIdx.x;
    if (i < N) off[i] = 0;
}

__global__ __launch_bounds__(256) void k_count(const int* __restrict__ dst,
                                               int* __restrict__ off, int E) {
    int e = blockIdx.x * 256 + threadIdx.x;
    if (e < E) atomicAdd(&off[dst[e]], 1);
}

// Block-local exclusive scan of deg (in place) + dis = rsqrt(deg+1) + block sums.
__global__ __launch_bounds__(256) void k_scan_blk(int* __restrict__ off,
                                                  float* __restrict__ dis,
                                                  int* __restrict__ bsum, int N) {
    int t = threadIdx.x;
    int base = blockIdx.x * SCAN_TILE + t * 4;
    int4 d = make_int4(0, 0, 0, 0);
    if (base + 3 < N) d = *(const int4*)(off + base);
    else {
        if (base + 0 < N) d.x = off[base + 0];
        if (base + 1 < N) d.y = off[base + 1];
        if (base + 2 < N) d.z = off[base + 2];
    }
    if (base + 0 < N) dis[base + 0] = rsqrtf((float)(d.x + 1));
    if (base + 1 < N) dis[base + 1] = rsqrtf((float)(d.y + 1));
    if (base + 2 < N) dis[base + 2] = rsqrtf((float)(d.z + 1));
    if (base + 3 < N) dis[base + 3] = rsqrtf((float)(d.w + 1));

    int tsum = d.x + d.y + d.z + d.w;
    int lane = t & 63;
    int incl = tsum;
    #pragma unroll
    for (int ofs = 1; ofs < 64; ofs <<= 1) {
        int u = __shfl_up(incl, ofs);
        if (lane >= ofs) incl += u;
    }
    __shared__ int wsum[4];
    if (lane == 63) wsum[t >> 6] = incl;
    __syncthreads();
    int w = t >> 6;
    int woff = 0;
    for (int i = 0; i < w; ++i) woff += wsum[i];

    int run = woff + incl - tsum;  // exclusive prefix (block-local)
    if (base + 0 < N) off[base + 0] = run; run += d.x;
    if (base + 1 < N) off[base + 1] = run; run += d.y;
    if (base + 2 < N) off[base + 2] = run; run += d.z;
    if (base + 3 < N) off[base + 3] = run;
    if (t == 255) bsum[blockIdx.x] = woff + incl;  // block total
}

__global__ __launch_bounds__(256) void k_scan_add(int* __restrict__ off,
                                                  const int* __restrict__ bsum, int N) {
    int bid = blockIdx.x;
    if (bid == 0) return;
    int p = 0;
    for (int i = 0; i < bid; ++i) p += bsum[i];
    int base = bid * SCAN_TILE + threadIdx.x * 4;
    if (base + 3 < N) {
        int4 v = *(const int4*)(off + base);
        v.x += p; v.y += p; v.z += p; v.w += p;
        *(int4*)(off + base) = v;
    } else {
        if (base + 0 < N) off[base + 0] += p;
        if (base + 1 < N) off[base + 1] += p;
        if (base + 2 < N) off[base + 2] += p;
    }
}

// csr fill: pos = off[dst]++ ; csr[pos] = src. After this, off[v] = excl_prefix[v+1].
__global__ __launch_bounds__(256) void k_fill(const int* __restrict__ src,
                                              const int* __restrict__ dst,
                                              int* __restrict__ off,
                                              int* __restrict__ csr, int E) {
    int e = blockIdx.x * 256 + threadIdx.x;
    if (e >= E) return;
    int pos = atomicAdd(&off[dst[e]], 1);
    csr[pos] = src[e];
}

// Convert all 4 weight matrices (fp32 128x128) into MFMA B-fragment layout,
// bf16 hi/lo planes. Per matrix: [2 planes][4 ksteps][8 ctiles][64 lanes][8] ushort
// = 32768 ushorts = 64KB. Fragment semantic: lane = 16*((k%32)/8) + (col%16),
// j = k%8 holds B[k][col].
__global__ __launch_bounds__(256) void k_wconv(const float* __restrict__ W_in,
                                               const float* __restrict__ Ws,
                                               ushort* __restrict__ Wf) {
    int idx = blockIdx.x * 256 + threadIdx.x;   // 4 * 16384
    int m = idx >> 14;
    int e = idx & 16383;
    int k = e >> 7, col = e & 127;
    const float* srcm = (m == 0) ? W_in : (Ws + (m - 1) * 16384);
    float w = srcm[k * 128 + col];
    ushort hi = f2bf(w);
    ushort lo = f2bf(w - bf2f(hi));
    int ks = k >> 5, lk = (k >> 3) & 3, j = k & 7;
    int ct = col >> 4, lane = lk * 16 + (col & 15);
    int o = m * 32768 + (ks * 8 + ct) * 512 + lane * 8 + j;
    Wf[o] = hi;
    Wf[o + 16384] = lo;
}

// x (fp32) -> hh/hl bf16 split pair.
__global__ __launch_bounds__(256) void k_xconv(const float* __restrict__ x,
                                               ushort* __restrict__ hh,
                                               ushort* __restrict__ hl, int total4) {
    int i = blockIdx.x * 256 + threadIdx.x;
    if (i >= total4) return;
    float4 v = ((const float4*)x)[i];
    ushort a0 = f2bf(v.x), a1 = f2bf(v.y), a2 = f2bf(v.z), a3 = f2bf(v.w);
    uint2 ph, pl;
    ph.x = (uint)a0 | ((uint)a1 << 16);
    ph.y = (uint)a2 | ((uint)a3 << 16);
    pl.x = (uint)f2bf(v.x - bf2f(a0)) | ((uint)f2bf(v.y - bf2f(a1)) << 16);
    pl.y = (uint)f2bf(v.z - bf2f(a2)) | ((uint)f2bf(v.w - bf2f(a3)) << 16);
    ((uint2*)hh)[i] = ph;
    ((uint2*)hl)[i] = pl;
}

// MFMA GEMM: out[M,128] = (Ahi+Alo)[M,128] @ W[128,128], 3-term bf16 split.
// Block = 4 waves, wave = one 16-row strip, full 128 cols (8 ctiles).
// BF16OUT: write hi/lo split pair (plus bias); else fp32 (times scale).
// In-place (outhi==Ahi) is safe: a wave reads only its own 16 rows.
template<int BF16OUT>
__global__ __launch_bounds__(256) void k_mgemm(const ushort* Ahi, const ushort* Alo,
                                               const ushort* __restrict__ Wf,
                                               const float* __restrict__ bias,
                                               const float* __restrict__ scale,
                                               float* outf, ushort* outhi,
                                               ushort* outlo, int M) {
    int l = threadIdx.x & 63;
    int strip = blockIdx.x * 4 + (threadIdx.x >> 6);
    int r0 = strip * 16;
    if (r0 >= M) return;
    int lr = l & 15, lk = l >> 4;
    const ushort* pa_hi = Ahi + (r0 + lr) * HDIM + lk * 8;
    const ushort* pa_lo = Alo + (r0 + lr) * HDIM + lk * 8;

    f4v acc[8];
    #pragma unroll
    for (int c = 0; c < 8; ++c) acc[c] = (f4v){0.f, 0.f, 0.f, 0.f};

    #pragma unroll
    for (int ks = 0; ks < 4; ++ks) {
        s8v ah = *(const s8v*)(pa_hi + ks * 32);
        s8v al = *(const s8v*)(pa_lo + ks * 32);
        const ushort* wb = Wf + (ks * 8) * 512 + l * 8;
        #pragma unroll
        for (int ct = 0; ct < 8; ++ct) {
            s8v bh = *(const s8v*)(wb + ct * 512);
            s8v bl = *(const s8v*)(wb + 16384 + ct * 512);
            acc[ct] = __builtin_amdgcn_mfma_f32_16x16x32_bf16(ah, bh, acc[ct], 0, 0, 0);
            acc[ct] = __builtin_amdgcn_mfma_f32_16x16x32_bf16(ah, bl, acc[ct], 0, 0, 0);
            acc[ct] = __builtin_amdgcn_mfma_f32_16x16x32_bf16(al, bh, acc[ct], 0, 0, 0);
        }
    }

    float bb[8];
    #pragma unroll
    for (int ct = 0; ct < 8; ++ct) bb[ct] = bias ? bias[ct * 16 + lr] : 0.f;
    float sc[4];
    #pragma unroll
    for (int j = 0; j < 4; ++j) sc[j] = scale ? scale[r0 + lk * 4 + j] : 1.f;

    #pragma unroll
    for (int ct = 0; ct < 8; ++ct) {
        #pragma unroll
        for (int j = 0; j < 4; ++j) {
            int row = r0 + lk * 4 + j;
            int col = ct * 16 + lr;
            float o = (acc[ct][j] + bb[ct]) * sc[j];
            if (BF16OUT) {
                ushort h = f2bf(o);
                outhi[row * HDIM + col] = h;
                outlo[row * HDIM + col] = f2bf(o - bf2f(h));
            } else {
                outf[row * HDIM + col] = o;
            }
        }
    }
}

// Pull aggregation over pre-scaled xw' (xw' = dis[row] * (h@W)).
// acc = xw'[v] + sum_{u in N(v)} xw'[u];  out = relu(dv*acc + b).
// LAST: write fp32 d_out; else write bf16 hi/lo split pair.
template<int LAST>
__global__ __launch_bounds__(256) void k_agg(const int* __restrict__ off,
                                             const int* __restrict__ csr,
                                             const float* __restrict__ dis,
                                             const float* __restrict__ xw,
                                             const float* __restrict__ b,
                                             float* __restrict__ outf,
                                             ushort* __restrict__ outhi,
                                             ushort* __restrict__ outlo, int N) {
    int nwaves = gridDim.x * 4;
    int wid = blockIdx.x * 4 + (threadIdx.x >> 6);
    int lane = threadIdx.x & 63;
    float2 bb = ((const float2*)b)[lane];

    for (int v = wid; v < N; v += nwaves) {
        int start = (v > 0) ? off[v - 1] : 0;   // off is post-fill: off[v] = excl[v+1]
        int end = off[v];
        float dv = dis[v];

        float2 acc = *((const float2*)(xw + (long long)v * HDIM) + lane);  // self term

        int i = start;
        for (; i + 8 <= end; i += 8) {
            int ib = __builtin_amdgcn_readfirstlane(i);
            int s0 = csr[ib + 0], s1 = csr[ib + 1], s2 = csr[ib + 2], s3 = csr[ib + 3];
            int s4 = csr[ib + 4], s5 = csr[ib + 5], s6 = csr[ib + 6], s7 = csr[ib + 7];
            float2 x0 = *((const float2*)(xw + (long long)s0 * HDIM) + lane);
            float2 x1 = *((const float2*)(xw + (long long)s1 * HDIM) + lane);
            float2 x2 = *((const float2*)(xw + (long long)s2 * HDIM) + lane);
            float2 x3 = *((const float2*)(xw + (long long)s3 * HDIM) + lane);
            float2 x4 = *((const float2*)(xw + (long long)s4 * HDIM) + lane);
            float2 x5 = *((const float2*)(xw + (long long)s5 * HDIM) + lane);
            float2 x6 = *((const float2*)(xw + (long long)s6 * HDIM) + lane);
            float2 x7 = *((const float2*)(xw + (long long)s7 * HDIM) + lane);
            acc.x += ((x0.x + x1.x) + (x2.x + x3.x)) + ((x4.x + x5.x) + (x6.x + x7.x));
            acc.y += ((x0.y + x1.y) + (x2.y + x3.y)) + ((x4.y + x5.y) + (x6.y + x7.y));
        }
        for (; i < end; ++i) {
            int s = csr[__builtin_amdgcn_readfirstlane(i)];
            float2 x0 = *((const float2*)(xw + (long long)s * HDIM) + lane);
            acc.x += x0.x; acc.y += x0.y;
        }

        float ox = fmaxf(fmaf(dv, acc.x, bb.x), 0.f);
        float oy = fmaxf(fmaf(dv, acc.y, bb.y), 0.f);
        if (LAST) {
            float2 o = make_float2(ox, oy);
            *((float2*)(outf + (long long)v * HDIM) + lane) = o;
        } else {
            ushort h0 = f2bf(ox), h1 = f2bf(oy);
            uint ph = (uint)h0 | ((uint)h1 << 16);
            uint pl = (uint)f2bf(ox - bf2f(h0)) | ((uint)f2bf(oy - bf2f(h1)) << 16);
            ((uint*)(outhi + (long long)v * HDIM))[lane] = ph;
            ((uint*)(outlo + (long long)v * HDIM))[lane] = pl;
        }
    }
}

extern "C" void kernel_launch(void* const* d_in, const int* in_sizes, int n_in,
                              void* d_out, int out_size, void* d_ws, size_t ws_size,
                              hipStream_t stream) {
    const float* x    = (const float*)d_in[0];
    const int*   ei   = (const int*)d_in[1];   // [2, E]: first E = src, next E = dst
    const float* W_in = (const float*)d_in[2];
    const float* b_in = (const float*)d_in[3];
    const float* Ws   = (const float*)d_in[4]; // [3,128,128]
    const float* bs   = (const float*)d_in[5]; // [3,128]

    const int N = in_sizes[0] / HDIM;
    const int E = in_sizes[1] / 2;
    const int* src = ei;
    const int* dst = ei + E;

    float*  dis = (float*)d_ws;                      // N floats
    int*    off = (int*)(dis + N);                   // N ints
    int*    csr = off + N;                           // E ints (first ~32 = scan bsums, transient)
    ushort* hh  = (ushort*)(csr + E);                // N*128 bf16 (h hi)
    ushort* hl  = hh + (long long)N * HDIM;          // N*128 bf16 (h lo)
    float*  xw  = (float*)(hl + (long long)N * HDIM);// N*128 floats (pre-scaled by dis)
    ushort* Wf  = (ushort*)d_out;                    // 4*64KB scratch, overwritten by last agg

    int nb_N    = (N + 255) / 256;
    int nb_E    = (E + 255) / 256;
    int nb_scan = (N + SCAN_TILE - 1) / SCAN_TILE;
    int strips  = (N + 15) / 16;
    int nb_mg   = (strips + 3) / 4;
    int nb_x4   = (N * (HDIM / 4) + 255) / 256;
    int nb_agg  = 2048;

    // CSR build + dis
    k_zero    <<<nb_N,    256, 0, stream>>>(off, N);
    k_count   <<<nb_E,    256, 0, stream>>>(dst, off, E);
    k_scan_blk<<<nb_scan, 256, 0, stream>>>(off, dis, csr, N);
    k_scan_add<<<nb_scan, 256, 0, stream>>>(off, csr, N);
    k_fill    <<<nb_E,    256, 0, stream>>>(src, dst, off, csr, E);

    // weight fragments (d_out scratch) + x -> bf16 split
    k_wconv<<<256, 256, 0, stream>>>(W_in, Ws, Wf);
    k_xconv<<<nb_x4, 256, 0, stream>>>(x, hh, hl, N * (HDIM / 4));

    // h0 = x @ W_in + b_in   (bf16-split output, in place: wave reads own rows only)
    k_mgemm<1><<<nb_mg, 256, 0, stream>>>(hh, hl, Wf, b_in, nullptr,
                                          nullptr, hh, hl, N);

    for (int layer = 0; layer < 3; ++layer) {
        const ushort* Wfm = Wf + (long long)(layer + 1) * 32768;
        const float* b = bs + (long long)layer * HDIM;
        // xw' = (h @ W) * dis[row]  (fp32 out)
        k_mgemm<0><<<nb_mg, 256, 0, stream>>>(hh, hl, Wfm, nullptr, dis,
                                              xw, nullptr, nullptr, N);
        if (layer == 2)
            k_agg<1><<<nb_agg, 256, 0, stream>>>(off, csr, dis, xw, b,
                                                 (float*)d_out, nullptr, nullptr, N);
        else
            k_agg<0><<<nb_agg, 256, 0, stream>>>(off, csr, dis, xw, b,
                                                 nullptr, hh, hl, N);
    }
}